// Round 3
// baseline (166.166 us; speedup 1.0000x reference)
//
#include <hip/hip_runtime.h>

#define IN_D 112
#define OUT_D 111
#define MDIM 16
#define DC 8   // d-outputs streamed per thread

// Lane layout: lane = 4*ci + q. ci = local column (0..15), q = channel quad
// (0..3, i.e. floats 4q..4q+3). Wave g covers output columns g*15 .. g*15+14.
//
// Round-2 findings: VGPR_Count=64 both with global-M and LDS-M -> the
// allocator REMATERIALIZES all 16 Mreg float4s every k-step (16 ds_read_b128)
// and the 12 quad-gather shuffles are ds_bpermute: ~290 DS-pipe cycles per
// k-step per wave. The per-CU LDS pipe (shared by 4 SIMDs) saturates at
// ~50 us -- matching the measured 56 us. SQ_LDS_BANK_CONFLICT=0 confirms
// it's instruction-count saturation, not conflicts.
//
// Round-3 fixes:
//  (a) Mreg is pinned via opaque `asm volatile` defs -> non-rematerializable,
//      must stay resident (budget 128 @ launch_bounds(256,4); demand ~120).
//      Success tell: VGPR_Count jumps 64 -> ~120-128.
//  (b) quad gathers (lane^1/2/3 within groups of 4) moved from ds_bpermute
//      to DPP quad_perm (VALU modifier, no DS pipe).
//  Remaining DS per k-step: only the 4 ds_bpermute of the w-shift (lane+4,
//  which crosses DPP 16-lane row boundaries at ci=3,7,11 so DPP can't do it).
__device__ __forceinline__ float4 f4add(float4 a, float4 b) {
    return make_float4(a.x + b.x, a.y + b.y, a.z + b.z, a.w + b.w);
}
__device__ __forceinline__ float4 shfl_down4(float4 v) {
    return make_float4(__shfl_down(v.x, 4, 64), __shfl_down(v.y, 4, 64),
                       __shfl_down(v.z, 4, 64), __shfl_down(v.w, 4, 64));
}

// DPP quad_perm: result lane j (in each group of 4) = src lane perm[j].
// xor1 -> [1,0,3,2] = 0xB1 ; xor2 -> [2,3,0,1] = 0x4E ; xor3 -> [3,2,1,0] = 0x1B
template <int CTRL>
__device__ __forceinline__ float dppf(float v) {
    return __int_as_float(
        __builtin_amdgcn_mov_dpp(__float_as_int(v), CTRL, 0xF, 0xF, false));
}
template <int CTRL>
__device__ __forceinline__ float4 dpp4(float4 v) {
    return make_float4(dppf<CTRL>(v.x), dppf<CTRL>(v.y),
                       dppf<CTRL>(v.z), dppf<CTRL>(v.w));
}

__device__ __forceinline__ void pin4(float4& v) {
    asm volatile("" : "+v"(v.x), "+v"(v.y), "+v"(v.z), "+v"(v.w));
}

__global__ __launch_bounds__(256, 4)
void spatial_dual_desc_kernel(const float* __restrict__ x,
                              const float* __restrict__ Mg,
                              float* __restrict__ out) {
    const int lane = threadIdx.x & 63;
    const int wid  = threadIdx.x >> 6;          // 0..3
    const int g    = blockIdx.x * 4 + wid;      // wave slot 0..7
    const int ci   = lane >> 2;                 // 0..15
    const int q    = lane & 3;                  // 0..3
    const int col  = g * 15 + ci;               // candidate output column (0..120)
    const int c    = (col < IN_D) ? col : (IN_D - 1);
    const int h    = blockIdx.y;
    const int d0   = blockIdx.z * DC;

    // Stage M (1 KB) into LDS once per block (broadcast-friendly source for
    // the one-time fragment build; never touched again after pinning).
    __shared__ float Ms[MDIM * MDIM];
    Ms[threadIdx.x] = Mg[threadIdx.x];
    __syncthreads();

    // Per-lane permuted M fragment: Mreg[i][m] = quad (q^m) of row (4q+i).
    // Pinned resident: the asm makes each value's def opaque so the register
    // allocator cannot re-load it from LDS inside the k-loop.
    float4 Mreg[4][4];
#pragma unroll
    for (int i = 0; i < 4; ++i)
#pragma unroll
        for (int m = 0; m < 4; ++m) {
            float4 v = *(const float4*)(&Ms[(4 * q + i) * MDIM + 4 * (q ^ m)]);
            pin4(v);
            Mreg[i][m] = v;
        }

    const size_t row_stride  = (size_t)IN_D * MDIM;          // h step (floats)
    const size_t slab_stride = (size_t)IN_D * row_stride;    // d step (floats)
    const float* bp = x + ((size_t)h * IN_D + c) * MDIM + 4 * q;

    // Prologue: slab d0 row pair -> rs_prev; prefetch slabs d0+1, d0+2.
    float4 a0 = *(const float4*)(bp + (size_t)d0 * slab_stride);
    float4 b0 = *(const float4*)(bp + (size_t)d0 * slab_stride + row_stride);
    float4 buf[2][2];
    buf[0][0] = *(const float4*)(bp + (size_t)(d0 + 1) * slab_stride);
    buf[0][1] = *(const float4*)(bp + (size_t)(d0 + 1) * slab_stride + row_stride);
    buf[1][0] = *(const float4*)(bp + (size_t)(d0 + 2) * slab_stride);
    buf[1][1] = *(const float4*)(bp + (size_t)(d0 + 2) * slab_stride + row_stride);

    float4 rs_prev = f4add(a0, b0);

#pragma unroll
    for (int k = 0; k < DC; ++k) {
        const int dcur = d0 + k;
        float4 ea = buf[k & 1][0];
        float4 eb = buf[k & 1][1];
        float4 rs_new = f4add(ea, eb);   // row-pair sum of slab dcur+1

        // Prefetch slab dcur+3 into the buffer just freed (depth-2 pipeline).
        if (k < DC - 2) {
            int dn = d0 + k + 3;
            if (dn > IN_D - 1) dn = IN_D - 1;
            const float* p = bp + (size_t)dn * slab_stride;
            buf[k & 1][0] = *(const float4*)p;
            buf[k & 1][1] = *(const float4*)(p + row_stride);
        }

        // d-pair, then w-pair (neighbor column = lane+4), per-quad.
        float4 s4 = f4add(rs_prev, rs_new);
        float4 w4 = f4add(s4, shfl_down4(s4));

        // Gather the other 3 quads of the window-sum vector via DPP quad_perm
        // (intra-quad lane^m exchange, VALU pipe -- no DS traffic).
        float4 p1 = dpp4<0xB1>(w4);
        float4 p2 = dpp4<0x4E>(w4);
        float4 p3 = dpp4<0x1B>(w4);

        float o[4];
#pragma unroll
        for (int i = 0; i < 4; ++i) {
            float acc;
            acc  = w4.x * Mreg[i][0].x + w4.y * Mreg[i][0].y + w4.z * Mreg[i][0].z + w4.w * Mreg[i][0].w;
            acc += p1.x * Mreg[i][1].x + p1.y * Mreg[i][1].y + p1.z * Mreg[i][1].z + p1.w * Mreg[i][1].w;
            acc += p2.x * Mreg[i][2].x + p2.y * Mreg[i][2].y + p2.z * Mreg[i][2].z + p2.w * Mreg[i][2].w;
            acc += p3.x * Mreg[i][3].x + p3.y * Mreg[i][3].y + p3.z * Mreg[i][3].z + p3.w * Mreg[i][3].w;
            o[i] = acc * 0.125f;
        }

        if (ci < 15 && col < OUT_D && dcur < OUT_D) {
            *(float4*)(out + (((size_t)dcur * OUT_D + h) * OUT_D + col) * MDIM + 4 * q)
                = make_float4(o[0], o[1], o[2], o[3]);
        }
        rs_prev = rs_new;
    }
}

extern "C" void kernel_launch(void* const* d_in, const int* in_sizes, int n_in,
                              void* d_out, int out_size, void* d_ws, size_t ws_size,
                              hipStream_t stream) {
    const float* x = (const float*)d_in[0];   // (112,112,112,16) fp32
    const float* M = (const float*)d_in[1];   // (16,16) fp32
    float* out = (float*)d_out;               // (111^3, 16) fp32

    dim3 block(256, 1, 1);
    dim3 grid(2, OUT_D, (OUT_D + DC - 1) / DC);   // 2 x 111 x 14
    spatial_dual_desc_kernel<<<grid, block, 0, stream>>>(x, M, out);
}

// Round 4
// 165.215 us; speedup vs baseline: 1.0058x; 1.0058x over previous
//
#include <hip/hip_runtime.h>

#define IN_D 112
#define OUT_D 111
#define MDIM 16
#define DC 8   // d-outputs streamed per thread

// Lane layout: lane = 4*ci + q. ci = local column (0..15), q = channel quad
// (0..3, i.e. floats 4q..4q+3). Wave g covers output columns g*15 .. g*15+14.
//
// Round 1-3 post-mortems, unified: VGPR_Count stayed 64 in ALL variants.
// The 64-float Mreg cannot be resident at 64 VGPRs, so the allocator
// re-supplied it per k-step from global (R1), LDS (R2), or scratch (R3,
// after pin4 blocked rematerialization). All three put 16 high-latency
// reloads on the k-step critical path -> ~1670 cyc/step wall vs ~250 cyc
// of real work; time pinned at 56-58 us regardless of DS/DPP changes.
// VALUBusy 22-31%, MfmaUtil 0, HBM 40% => latency-bound on reload stalls.
//
// Round-4 fix: amdgpu_waves_per_eu(4,4). __launch_bounds__' 2nd arg is only
// a MINIMUM waves/EU; the allocator still targeted 8 waves/SIMD (64 VGPR)
// and spilled. Capping max waves/EU at 4 removes the incentive: VGPR budget
// 128, live demand ~116, Mreg stays truly resident. Success tell:
// VGPR_Count ~110-128.
__device__ __forceinline__ float4 f4add(float4 a, float4 b) {
    return make_float4(a.x + b.x, a.y + b.y, a.z + b.z, a.w + b.w);
}
__device__ __forceinline__ float4 shfl_down4(float4 v) {
    return make_float4(__shfl_down(v.x, 4, 64), __shfl_down(v.y, 4, 64),
                       __shfl_down(v.z, 4, 64), __shfl_down(v.w, 4, 64));
}

// DPP quad_perm: result lane j (in each group of 4) = src lane perm[j].
// xor1 -> [1,0,3,2] = 0xB1 ; xor2 -> [2,3,0,1] = 0x4E ; xor3 -> [3,2,1,0] = 0x1B
template <int CTRL>
__device__ __forceinline__ float dppf(float v) {
    return __int_as_float(
        __builtin_amdgcn_mov_dpp(__float_as_int(v), CTRL, 0xF, 0xF, false));
}
template <int CTRL>
__device__ __forceinline__ float4 dpp4(float4 v) {
    return make_float4(dppf<CTRL>(v.x), dppf<CTRL>(v.y),
                       dppf<CTRL>(v.z), dppf<CTRL>(v.w));
}

__device__ __forceinline__ void pin4(float4& v) {
    asm volatile("" : "+v"(v.x), "+v"(v.y), "+v"(v.z), "+v"(v.w));
}

__global__ __launch_bounds__(256)
__attribute__((amdgpu_waves_per_eu(4, 4)))
void spatial_dual_desc_kernel(const float* __restrict__ x,
                              const float* __restrict__ Mg,
                              float* __restrict__ out) {
    const int lane = threadIdx.x & 63;
    const int wid  = threadIdx.x >> 6;          // 0..3
    const int g    = blockIdx.x * 4 + wid;      // wave slot 0..7
    const int ci   = lane >> 2;                 // 0..15
    const int q    = lane & 3;                  // 0..3
    const int col  = g * 15 + ci;               // candidate output column (0..120)
    const int c    = (col < IN_D) ? col : (IN_D - 1);
    const int h    = blockIdx.y;
    const int d0   = blockIdx.z * DC;

    // Stage M (1 KB) into LDS once per block (broadcast source for the
    // one-time fragment build; never touched again afterwards).
    __shared__ float Ms[MDIM * MDIM];
    Ms[threadIdx.x] = Mg[threadIdx.x];
    __syncthreads();

    // Per-lane permuted M fragment: Mreg[i][m] = quad (q^m) of row (4q+i).
    // With the 128-VGPR budget this stays resident; pin4 additionally blocks
    // rematerialization from LDS.
    float4 Mreg[4][4];
#pragma unroll
    for (int i = 0; i < 4; ++i)
#pragma unroll
        for (int m = 0; m < 4; ++m) {
            float4 v = *(const float4*)(&Ms[(4 * q + i) * MDIM + 4 * (q ^ m)]);
            pin4(v);
            Mreg[i][m] = v;
        }

    const size_t row_stride  = (size_t)IN_D * MDIM;          // h step (floats)
    const size_t slab_stride = (size_t)IN_D * row_stride;    // d step (floats)
    const float* bp = x + ((size_t)h * IN_D + c) * MDIM + 4 * q;

    // Prologue: slab d0 row pair -> rs_prev; prefetch slabs d0+1, d0+2.
    float4 a0 = *(const float4*)(bp + (size_t)d0 * slab_stride);
    float4 b0 = *(const float4*)(bp + (size_t)d0 * slab_stride + row_stride);
    float4 buf[2][2];
    buf[0][0] = *(const float4*)(bp + (size_t)(d0 + 1) * slab_stride);
    buf[0][1] = *(const float4*)(bp + (size_t)(d0 + 1) * slab_stride + row_stride);
    buf[1][0] = *(const float4*)(bp + (size_t)(d0 + 2) * slab_stride);
    buf[1][1] = *(const float4*)(bp + (size_t)(d0 + 2) * slab_stride + row_stride);

    float4 rs_prev = f4add(a0, b0);

#pragma unroll
    for (int k = 0; k < DC; ++k) {
        const int dcur = d0 + k;
        float4 ea = buf[k & 1][0];
        float4 eb = buf[k & 1][1];
        float4 rs_new = f4add(ea, eb);   // row-pair sum of slab dcur+1

        // Prefetch slab dcur+3 into the buffer just freed (depth-2 pipeline).
        if (k < DC - 2) {
            int dn = d0 + k + 3;
            if (dn > IN_D - 1) dn = IN_D - 1;
            const float* p = bp + (size_t)dn * slab_stride;
            buf[k & 1][0] = *(const float4*)p;
            buf[k & 1][1] = *(const float4*)(p + row_stride);
        }

        // d-pair, then w-pair (neighbor column = lane+4), per-quad.
        float4 s4 = f4add(rs_prev, rs_new);
        float4 w4 = f4add(s4, shfl_down4(s4));

        // Gather the other 3 quads of the window-sum vector via DPP quad_perm
        // (intra-quad lane^m exchange, VALU pipe -- no DS traffic).
        float4 p1 = dpp4<0xB1>(w4);
        float4 p2 = dpp4<0x4E>(w4);
        float4 p3 = dpp4<0x1B>(w4);

        float o[4];
#pragma unroll
        for (int i = 0; i < 4; ++i) {
            float acc;
            acc  = w4.x * Mreg[i][0].x + w4.y * Mreg[i][0].y + w4.z * Mreg[i][0].z + w4.w * Mreg[i][0].w;
            acc += p1.x * Mreg[i][1].x + p1.y * Mreg[i][1].y + p1.z * Mreg[i][1].z + p1.w * Mreg[i][1].w;
            acc += p2.x * Mreg[i][2].x + p2.y * Mreg[i][2].y + p2.z * Mreg[i][2].z + p2.w * Mreg[i][2].w;
            acc += p3.x * Mreg[i][3].x + p3.y * Mreg[i][3].y + p3.z * Mreg[i][3].z + p3.w * Mreg[i][3].w;
            o[i] = acc * 0.125f;
        }

        if (ci < 15 && col < OUT_D && dcur < OUT_D) {
            *(float4*)(out + (((size_t)dcur * OUT_D + h) * OUT_D + col) * MDIM + 4 * q)
                = make_float4(o[0], o[1], o[2], o[3]);
        }
        rs_prev = rs_new;
    }
}

extern "C" void kernel_launch(void* const* d_in, const int* in_sizes, int n_in,
                              void* d_out, int out_size, void* d_ws, size_t ws_size,
                              hipStream_t stream) {
    const float* x = (const float*)d_in[0];   // (112,112,112,16) fp32
    const float* M = (const float*)d_in[1];   // (16,16) fp32
    float* out = (float*)d_out;               // (111^3, 16) fp32

    dim3 block(256, 1, 1);
    dim3 grid(2, OUT_D, (OUT_D + DC - 1) / DC);   // 2 x 111 x 14
    spatial_dual_desc_kernel<<<grid, block, 0, stream>>>(x, M, out);
}

// Round 5
// 160.850 us; speedup vs baseline: 1.0331x; 1.0271x over previous
//
#include <hip/hip_runtime.h>

#define IN_D 112
#define OUT_D 111
#define MDIM 16
#define DC 4            // d-outputs per thread (was 8)
#define NSLAB (DC + 1)  // slabs needed: d0 .. d0+DC (R1=2 window)

// Lane layout: lane = 4*ci + q. ci = local column (0..15), q = channel quad.
// Wave g covers output columns g*15 .. g*15+14 (16 input cols, 15 outputs).
//
// Rounds 1-4 post-mortem: time was invariant (56-58 us) across M served from
// global (R1) / LDS (R2) / pinned+scratch (R3/R4) and across -12 DS ops
// (DPP, R3): M supply was NEVER the critical path. Counters show ~75% of
// each step-slot is memory stall with <1 outstanding load per wave: the
// rolling depth-2 prefetch never builds depth at the 64-VGPR allocation,
// so each k-step exposes a full HBM/L3 round-trip. Kernel is latency-bound
// on slab loads, not BW (40%), not VALU (22%), not DS (0 conflicts).
//
// Round-5 restructure:
//  (a) DC=4, grid 2x111x28 = 6216 blocks -> 2x waves for latency hiding.
//  (b) ALL 10 slab-row loads (5 slabs x 2 rows) issued in the prologue,
//      consumed with descending vmcnt -> up to 10 KB in flight per wave.
//  (c) broadcast-u matmul: u_j = quad-bcast_j(w4) gives each lane the full
//      16-vector in NATURAL order, so M is consumed as natural rows
//      (remat, if any, is 8 ds_read_b128/step instead of 16 permuted).
__device__ __forceinline__ float4 f4add(float4 a, float4 b) {
    return make_float4(a.x + b.x, a.y + b.y, a.z + b.z, a.w + b.w);
}
__device__ __forceinline__ float4 shfl_down4(float4 v) {
    return make_float4(__shfl_down(v.x, 4, 64), __shfl_down(v.y, 4, 64),
                       __shfl_down(v.z, 4, 64), __shfl_down(v.w, 4, 64));
}

// DPP quad_perm. Broadcast lane j of each quad: ctrl = j*0x55.
template <int CTRL>
__device__ __forceinline__ float dppf(float v) {
    return __int_as_float(
        __builtin_amdgcn_mov_dpp(__float_as_int(v), CTRL, 0xF, 0xF, false));
}
template <int CTRL>
__device__ __forceinline__ float4 dpp4(float4 v) {
    return make_float4(dppf<CTRL>(v.x), dppf<CTRL>(v.y),
                       dppf<CTRL>(v.z), dppf<CTRL>(v.w));
}
__device__ __forceinline__ float dot4(float4 a, float4 b) {
    return a.x * b.x + a.y * b.y + a.z * b.z + a.w * b.w;
}

__global__ __launch_bounds__(256)
void spatial_dual_desc_kernel(const float* __restrict__ x,
                              const float* __restrict__ Mg,
                              float* __restrict__ out) {
    const int lane = threadIdx.x & 63;
    const int wid  = threadIdx.x >> 6;          // 0..3
    const int g    = blockIdx.x * 4 + wid;      // wave slot 0..7
    const int ci   = lane >> 2;                 // 0..15
    const int q    = lane & 3;                  // 0..3
    const int col  = g * 15 + ci;               // candidate output column
    const int c    = (col < IN_D) ? col : (IN_D - 1);
    const int h    = blockIdx.y;
    const int d0   = blockIdx.z * DC;

    // Stage M (1 KB) into LDS once per block.
    __shared__ float Ms[MDIM * MDIM];
    Ms[threadIdx.x] = Mg[threadIdx.x];
    __syncthreads();   // before any global loads so the barrier drain is free

    const size_t row_stride  = (size_t)IN_D * MDIM;          // h step (floats)
    const size_t slab_stride = (size_t)IN_D * row_stride;    // d step (floats)
    const float* bp = x + ((size_t)h * IN_D + c) * MDIM + 4 * q;

    // Issue ALL slab loads up front: 5 slabs x 2 rows = 10 x 1KB/wave.
    float4 ra[NSLAB], rb[NSLAB];
#pragma unroll
    for (int j = 0; j < NSLAB; ++j) {
        int dj = d0 + j;
        if (dj > IN_D - 1) dj = IN_D - 1;
        const float* p = bp + (size_t)dj * slab_stride;
        ra[j] = *(const float4*)p;
        rb[j] = *(const float4*)(p + row_stride);
    }

    // M as natural rows: Mrow[i][j] = cols 4j..4j+3 of row (4q+i).
    float4 Mrow[4][4];
#pragma unroll
    for (int i = 0; i < 4; ++i)
#pragma unroll
        for (int j = 0; j < 4; ++j)
            Mrow[i][j] = *(const float4*)(&Ms[(4 * q + i) * MDIM + 4 * j]);

    // Row-pair sums per slab (consumes loads in issue order).
    float4 rs[NSLAB];
#pragma unroll
    for (int j = 0; j < NSLAB; ++j)
        rs[j] = f4add(ra[j], rb[j]);

#pragma unroll
    for (int k = 0; k < DC; ++k) {
        const int dcur = d0 + k;

        // d-pair, then w-pair (neighbor column = lane+4).
        float4 s4 = f4add(rs[k], rs[k + 1]);
        float4 w4 = f4add(s4, shfl_down4(s4));

        // Broadcast each quad's value to all 4 lanes of the quad: every lane
        // now holds the full 16-component window vector in natural order.
        float4 u0 = dpp4<0x00>(w4);
        float4 u1 = dpp4<0x55>(w4);
        float4 u2 = dpp4<0xAA>(w4);
        float4 u3 = dpp4<0xFF>(w4);

        float o[4];
#pragma unroll
        for (int i = 0; i < 4; ++i) {
            float acc = dot4(u0, Mrow[i][0]) + dot4(u1, Mrow[i][1])
                      + dot4(u2, Mrow[i][2]) + dot4(u3, Mrow[i][3]);
            o[i] = acc * 0.125f;
        }

        if (ci < 15 && col < OUT_D && dcur < OUT_D) {
            *(float4*)(out + (((size_t)dcur * OUT_D + h) * OUT_D + col) * MDIM + 4 * q)
                = make_float4(o[0], o[1], o[2], o[3]);
        }
    }
}

extern "C" void kernel_launch(void* const* d_in, const int* in_sizes, int n_in,
                              void* d_out, int out_size, void* d_ws, size_t ws_size,
                              hipStream_t stream) {
    const float* x = (const float*)d_in[0];   // (112,112,112,16) fp32
    const float* M = (const float*)d_in[1];   // (16,16) fp32
    float* out = (float*)d_out;               // (111^3, 16) fp32

    dim3 block(256, 1, 1);
    dim3 grid(2, OUT_D, (OUT_D + DC - 1) / DC);   // 2 x 111 x 28
    spatial_dual_desc_kernel<<<grid, block, 0, stream>>>(x, M, out);
}